// Round 6
// baseline (944.860 us; speedup 1.0000x reference)
//
#include <hip/hip_runtime.h>
#include <hip/hip_bf16.h>

#define EMB 768
#define NHEADS 8
#define HDIM 96
#define SEQ 2048
#define BATCH 4
#define QKV_COLS 2304
#define PB ((size_t)SEQ * EMB)   // per-batch elements (x / q+k+v per batch each = N*EMB)

typedef _Float16 f16;
typedef _Float16 f16x8 __attribute__((ext_vector_type(8)));
typedef float f32x4 __attribute__((ext_vector_type(4)));

// ---------------- fp32 -> fp16 conversion kernels ----------------
__global__ __launch_bounds__(256) void conv_copy_k(const float* __restrict__ in, size_t in_off,
                                                   f16* __restrict__ out, int n) {
  int idx = blockIdx.x * 256 + threadIdx.x;
  if (idx >= n) return;
  out[idx] = (f16)in[in_off + (size_t)idx];
}

__global__ __launch_bounds__(256) void conv_transpose_k(const float* __restrict__ in,
                                                        f16* __restrict__ out,
                                                        int R, int C) {
  int idx = blockIdx.x * 256 + threadIdx.x;
  if (idx >= R * C) return;
  int r = idx / C, c = idx - r * C;
  out[c * R + r] = (f16)in[idx];
}

__global__ __launch_bounds__(256) void copy_f32_k(const float* __restrict__ in,
                                                  float* __restrict__ out, int n) {
  int idx = blockIdx.x * 256 + threadIdx.x;
  if (idx >= n) return;
  out[idx] = in[idx];
}

// ---------------- bt-GEMM: C[M,N] = A[M,K] @ Bt[N,K]^T + bias (fp16 in, fp32 acc) ----
// MODE 0: fp32 store to Cout [M,N]
// MODE 1: qkv scatter (group-local): col c -> h=c/288, d=(c%288)/3, s=c%3 ; row -> (b_local,n)
template<int MODE>
__global__ __launch_bounds__(256) void gemm_bt(
    const f16* __restrict__ A, const f16* __restrict__ Bt,
    const float* __restrict__ bias, float* __restrict__ Cout,
    f16* __restrict__ Q, f16* __restrict__ K, f16* __restrict__ Vt,
    int M, int N, int Kd)
{
  __shared__ f16 sA[128][32];
  __shared__ f16 sB[128][32];
  const int tid  = threadIdx.x;
  const int wave = tid >> 6, lane = tid & 63;
  const int quad = lane >> 4, l16 = lane & 15;
  const int tile_m = blockIdx.y * 128, tile_n = blockIdx.x * 128;
  const int wm = (wave >> 1) * 64, wn = (wave & 1) * 64;

  f32x4 acc[4][4];
  for (int i = 0; i < 4; i++)
    for (int j = 0; j < 4; j++)
      acc[i][j] = f32x4{0.f, 0.f, 0.f, 0.f};

  const int r0 = tid >> 2;        // 0..63
  const int c8 = (tid & 3) * 8;   // 0,8,16,24

  for (int k0 = 0; k0 < Kd; k0 += 32) {
    __syncthreads();
    *(uint4*)&sA[r0][c8]      = *(const uint4*)(A  + (size_t)(tile_m + r0)      * Kd + k0 + c8);
    *(uint4*)&sA[r0 + 64][c8] = *(const uint4*)(A  + (size_t)(tile_m + r0 + 64) * Kd + k0 + c8);
    *(uint4*)&sB[r0][c8]      = *(const uint4*)(Bt + (size_t)(tile_n + r0)      * Kd + k0 + c8);
    *(uint4*)&sB[r0 + 64][c8] = *(const uint4*)(Bt + (size_t)(tile_n + r0 + 64) * Kd + k0 + c8);
    __syncthreads();

    f16x8 af[4], bfr[4];
    for (int i = 0; i < 4; i++) af[i]  = *(const f16x8*)&sA[wm + i * 16 + l16][quad * 8];
    for (int j = 0; j < 4; j++) bfr[j] = *(const f16x8*)&sB[wn + j * 16 + l16][quad * 8];
    for (int i = 0; i < 4; i++)
      for (int j = 0; j < 4; j++)
        acc[i][j] = __builtin_amdgcn_mfma_f32_16x16x32_f16(af[i], bfr[j], acc[i][j], 0, 0, 0);
  }

  // epilogue: C layout col=lane&15, row=quad*4+reg  [m89/m91 verified; dtype-independent]
  for (int j = 0; j < 4; j++) {
    const int col = tile_n + wn + j * 16 + l16;
    const float bv = bias[col];
    int h = 0, d = 0, s = 0;
    if (MODE == 1) {
      h = col / 288;
      int rem = col - h * 288;
      d = rem / 3;
      s = rem - d * 3;
    }
    for (int i = 0; i < 4; i++) {
      for (int r = 0; r < 4; r++) {
        const int row = tile_m + wm + i * 16 + quad * 4 + r;
        const float fv = acc[i][j][r] + bv;
        if (MODE == 0) {
          Cout[(size_t)row * N + col] = fv;
        } else {
          const f16 o = (f16)fv;
          const int b = row >> 11, n = row & 2047;   // b = group-local batch
          const size_t bh = (size_t)(b * NHEADS + h);
          if (s == 0)      Q [(bh * SEQ + n) * HDIM + d] = o;
          else if (s == 1) K [(bh * SEQ + n) * HDIM + d] = o;
          else             Vt[(bh * HDIM + d) * SEQ + n] = o;
        }
      }
    }
  }
}

// ---------------- flash attention ----------------
// grid: (SEQ/128, bpg*NHEADS); 256 threads = 4 waves; wave w owns q rows [w*32, w*32+32)
__global__ __launch_bounds__(256) void attn_k(
    const f16* __restrict__ Q, const f16* __restrict__ K,
    const f16* __restrict__ Vt, f16* __restrict__ Out /* [bpg,N,EMB] f16 */)
{
  __shared__ f16 sP[128][128];  // per-wave private 32-row slices; no barriers needed
  const int tid  = threadIdx.x;
  const int wave = tid >> 6, lane = tid & 63;
  const int quad = lane >> 4, l16 = lane & 15;
  const int qt = blockIdx.x;
  const int bh = blockIdx.y;           // group-local
  const int b = bh >> 3, h = bh & 7;   // group-local batch

  const f16* Qb = Q  + ((size_t)bh * SEQ + qt * 128) * HDIM;
  const f16* Kb = K  + (size_t)bh * SEQ * HDIM;
  const f16* Vb = Vt + (size_t)bh * HDIM * SEQ;

  // Q fragments in registers: A-operand A[m=l16][k=quad*8+j]
  f16x8 qf[2][3];
  for (int ti = 0; ti < 2; ti++)
    for (int kc = 0; kc < 3; kc++)
      qf[ti][kc] = *(const f16x8*)(Qb + (size_t)(wave * 32 + ti * 16 + l16) * HDIM + kc * 32 + quad * 8);

  f32x4 oacc[2][6];
  for (int ti = 0; ti < 2; ti++)
    for (int dj = 0; dj < 6; dj++)
      oacc[ti][dj] = f32x4{0.f, 0.f, 0.f, 0.f};
  float m_run[2][4], l_run[2][4];
  for (int ti = 0; ti < 2; ti++)
    for (int r = 0; r < 4; r++) { m_run[ti][r] = -1e30f; l_run[ti][r] = 0.f; }

  for (int kt = 0; kt < SEQ / 128; kt++) {
    f32x4 sacc[2][8];
    for (int ti = 0; ti < 2; ti++)
      for (int j = 0; j < 8; j++)
        sacc[ti][j] = f32x4{0.f, 0.f, 0.f, 0.f};
    for (int kc = 0; kc < 3; kc++) {
      for (int j = 0; j < 8; j++) {
        f16x8 kf = *(const f16x8*)(Kb + (size_t)(kt * 128 + j * 16 + l16) * HDIM + kc * 32 + quad * 8);
        sacc[0][j] = __builtin_amdgcn_mfma_f32_16x16x32_f16(qf[0][kc], kf, sacc[0][j], 0, 0, 0);
        sacc[1][j] = __builtin_amdgcn_mfma_f32_16x16x32_f16(qf[1][kc], kf, sacc[1][j], 0, 0, 0);
      }
    }

    float alpha[2][4];
    for (int ti = 0; ti < 2; ti++) {
      for (int r = 0; r < 4; r++) {
        float mx = sacc[ti][0][r];
        for (int j = 1; j < 8; j++) mx = fmaxf(mx, sacc[ti][j][r]);
        for (int m = 1; m < 16; m <<= 1) mx = fmaxf(mx, __shfl_xor(mx, m));
        const float nm = fmaxf(m_run[ti][r], mx);
        alpha[ti][r] = __expf(m_run[ti][r] - nm);
        m_run[ti][r] = nm;
        float rs = 0.f;
        const int prow = wave * 32 + ti * 16 + quad * 4 + r;
        for (int j = 0; j < 8; j++) {
          const float p = __expf(sacc[ti][j][r] - nm);
          rs += p;
          sP[prow][j * 16 + l16] = (f16)p;
        }
        for (int m = 1; m < 16; m <<= 1) rs += __shfl_xor(rs, m);
        l_run[ti][r] = l_run[ti][r] * alpha[ti][r] + rs;
      }
    }

    for (int ti = 0; ti < 2; ti++)
      for (int dj = 0; dj < 6; dj++)
        for (int r = 0; r < 4; r++)
          oacc[ti][dj][r] *= alpha[ti][r];

    for (int kc2 = 0; kc2 < 4; kc2++) {
      f16x8 pf0 = *(const f16x8*)&sP[wave * 32 + 0 * 16 + l16][kc2 * 32 + quad * 8];
      f16x8 pf1 = *(const f16x8*)&sP[wave * 32 + 1 * 16 + l16][kc2 * 32 + quad * 8];
      for (int dj = 0; dj < 6; dj++) {
        f16x8 vf = *(const f16x8*)(Vb + (size_t)(dj * 16 + l16) * SEQ + kt * 128 + kc2 * 32 + quad * 8);
        oacc[0][dj] = __builtin_amdgcn_mfma_f32_16x16x32_f16(pf0, vf, oacc[0][dj], 0, 0, 0);
        oacc[1][dj] = __builtin_amdgcn_mfma_f32_16x16x32_f16(pf1, vf, oacc[1][dj], 0, 0, 0);
      }
    }
  }

  const float inv_scale = 0.10206207261596577f;  // 1/sqrt(96), applied AFTER softmax per ref
  for (int ti = 0; ti < 2; ti++) {
    for (int r = 0; r < 4; r++) {
      const int qrow = qt * 128 + wave * 32 + ti * 16 + quad * 4 + r;
      const float invl = inv_scale / l_run[ti][r];
      const size_t base = ((size_t)b * SEQ + qrow) * EMB + h * HDIM;
      for (int dj = 0; dj < 6; dj++) {
        Out[base + dj * 16 + l16] = (f16)(oacc[ti][dj][r] * invl);
      }
    }
  }
}

// ---------------- launch ----------------
extern "C" void kernel_launch(void* const* d_in, const int* in_sizes, int n_in,
                              void* d_out, int out_size, void* d_ws, size_t ws_size,
                              hipStream_t stream) {
  const float* x      = (const float*)d_in[0];
  const float* w_qkv  = (const float*)d_in[1];
  const float* b_qkv  = (const float*)d_in[2];
  const float* w_proj = (const float*)d_in[3];
  const float* b_proj = (const float*)d_in[4];
  float* outF = (float*)d_out;   // fp32 output

  // ws footprint: fixed (~4.74MB) + bpg * 12.58MB (Q,K,Vt,attn f16). Pick bpg.
  const size_t fixed = 256 + (size_t)QKV_COLS * EMB * 2 + (size_t)EMB * EMB * 2
                     + QKV_COLS * 4 + EMB * 4 + 256;
  int bpg = (ws_size >= fixed + (size_t)2 * 4 * PB * 2) ? 2 : 1;

  char* ws = (char*)d_ws;
  ws += 256;
  f16*   wqkvT  = (f16*)ws;   ws += (size_t)QKV_COLS * EMB * 2;
  f16*   wprojT = (f16*)ws;   ws += (size_t)EMB * EMB * 2;
  float* bq     = (float*)ws; ws += (size_t)QKV_COLS * 4;
  float* bp     = (float*)ws; ws += (size_t)EMB * 4 + 256;
  f16* Q    = (f16*)ws;       ws += (size_t)bpg * PB * 2;
  f16* K    = (f16*)ws;       ws += (size_t)bpg * PB * 2;
  f16* Vt   = (f16*)ws;       ws += (size_t)bpg * PB * 2;
  f16* attn = (f16*)ws;       ws += (size_t)bpg * PB * 2;

  conv_transpose_k<<<(EMB * QKV_COLS + 255) / 256, 256, 0, stream>>>(w_qkv, wqkvT, EMB, QKV_COLS);
  conv_transpose_k<<<(EMB * EMB + 255) / 256, 256, 0, stream>>>(w_proj, wprojT, EMB, EMB);
  copy_f32_k<<<(QKV_COLS + 255) / 256, 256, 0, stream>>>(b_qkv, bq, QKV_COLS);
  copy_f32_k<<<(EMB + 255) / 256, 256, 0, stream>>>(b_proj, bp, EMB);

  const int ngroups = BATCH / bpg;
  for (int g = 0; g < ngroups; g++) {
    const size_t goff = (size_t)g * bpg * PB;       // element offset into x / out
    f16* xg = (f16*)(outF + goff);                  // stage f16 x inside fp32 out region (dead before proj writes)
    const int gelems = (int)((size_t)bpg * PB);

    conv_copy_k<<<(gelems + 255) / 256, 256, 0, stream>>>(x, goff, xg, gelems);

    dim3 g1(QKV_COLS / 128, bpg * SEQ / 128);
    gemm_bt<1><<<g1, 256, 0, stream>>>(xg, wqkvT, bq, nullptr, Q, K, Vt,
                                       bpg * SEQ, QKV_COLS, EMB);

    dim3 g2(SEQ / 128, bpg * NHEADS);
    attn_k<<<g2, 256, 0, stream>>>(Q, K, Vt, attn);

    dim3 g3(EMB / 128, bpg * SEQ / 128);
    gemm_bt<0><<<g3, 256, 0, stream>>>(attn, wprojT, bp, outF + goff,
                                       nullptr, nullptr, nullptr,
                                       bpg * SEQ, EMB, EMB);
  }
}

// Round 7
// 736.422 us; speedup vs baseline: 1.2830x; 1.2830x over previous
//
#include <hip/hip_runtime.h>
#include <hip/hip_bf16.h>

#define EMB 768
#define NHEADS 8
#define HDIM 96
#define SEQ 2048
#define BATCH 4
#define QKV_COLS 2304
#define PB ((size_t)SEQ * EMB)   // per-batch elements

typedef _Float16 f16;
typedef _Float16 f16x8 __attribute__((ext_vector_type(8)));
typedef float f32x4 __attribute__((ext_vector_type(4)));

__device__ __forceinline__ void gl_lds16(const f16* g, f16* l) {
  __builtin_amdgcn_global_load_lds((const __attribute__((address_space(1))) void*)g,
                                   (__attribute__((address_space(3))) void*)l, 16, 0, 0);
}
__device__ __forceinline__ f32x4 shflx4(f32x4 v, int m) {
  f32x4 r;
  r[0] = __shfl_xor(v[0], m); r[1] = __shfl_xor(v[1], m);
  r[2] = __shfl_xor(v[2], m); r[3] = __shfl_xor(v[3], m);
  return r;
}
__device__ __forceinline__ f32x4 vmax4(f32x4 a, f32x4 b) {
  f32x4 r;
  r[0] = fmaxf(a[0], b[0]); r[1] = fmaxf(a[1], b[1]);
  r[2] = fmaxf(a[2], b[2]); r[3] = fmaxf(a[3], b[3]);
  return r;
}

// ---------------- fp32 -> fp16 conversion ----------------
// 8 elements per thread (2 float4 reads -> 1 uint4 store)
__global__ __launch_bounds__(256) void conv_x8_k(const float* __restrict__ in, size_t in_off,
                                                 f16* __restrict__ out, int n8) {
  int i = blockIdx.x * 256 + threadIdx.x;
  if (i >= n8) return;
  const float4 a = *(const float4*)(in + in_off + (size_t)i * 8);
  const float4 b = *(const float4*)(in + in_off + (size_t)i * 8 + 4);
  f16x8 o;
  o[0] = (f16)a.x; o[1] = (f16)a.y; o[2] = (f16)a.z; o[3] = (f16)a.w;
  o[4] = (f16)b.x; o[5] = (f16)b.y; o[6] = (f16)b.z; o[7] = (f16)b.w;
  *(f16x8*)(out + (size_t)i * 8) = o;
}

__global__ __launch_bounds__(256) void conv_transpose_k(const float* __restrict__ in,
                                                        f16* __restrict__ out,
                                                        int R, int C) {
  int idx = blockIdx.x * 256 + threadIdx.x;
  if (idx >= R * C) return;
  int r = idx / C, c = idx - r * C;
  out[c * R + r] = (f16)in[idx];
}

__global__ __launch_bounds__(256) void copy_f32_k(const float* __restrict__ in,
                                                  float* __restrict__ out, int n) {
  int idx = blockIdx.x * 256 + threadIdx.x;
  if (idx >= n) return;
  out[idx] = in[idx];
}

// ---------------- bt-GEMM: C[M,N] = A[M,K] @ Bt[N,K]^T + bias (m97-style staging) ----
// MODE 0: fp32 store to Cout [M,N]
// MODE 1: qkv scatter: col c -> h=c/288, d=(c%288)/3, s=c%3 ; row -> (bofs + row>>11, n)
template<int MODE>
__global__ __launch_bounds__(256) void gemm_bt(
    const f16* __restrict__ A, const f16* __restrict__ Bt,
    const float* __restrict__ bias, float* __restrict__ Cout,
    f16* __restrict__ Q, f16* __restrict__ K, f16* __restrict__ Vt,
    int M, int N, int Kd, int bofs)
{
  __shared__ f16 sA[128 * 32];
  __shared__ f16 sB[128 * 32];
  const int tid  = threadIdx.x;
  const int wave = tid >> 6, lane = tid & 63;
  const int quad = lane >> 4, l16 = lane & 15;
  const int tile_m = blockIdx.y * 128, tile_n = blockIdx.x * 128;
  const int wm = (wave >> 1) * 64, wn = (wave & 1) * 64;

  f32x4 acc[4][4];
  for (int i = 0; i < 4; i++)
    for (int j = 0; j < 4; j++)
      acc[i][j] = f32x4{0.f, 0.f, 0.f, 0.f};

  for (int k0 = 0; k0 < Kd; k0 += 32) {
    __syncthreads();
    // async global->LDS, 16B per lane; LDS dest wave-uniform base + lane*16
#pragma unroll
    for (int it = 0; it < 2; it++) {
      const int ch  = (it * 4 + wave) * 64 + lane;   // 0..511
      const int row = ch >> 2, c8 = (ch & 3) * 8;
      gl_lds16(A  + (size_t)(tile_m + row) * Kd + k0 + c8, &sA[(it * 4 + wave) * 512]);
      gl_lds16(Bt + (size_t)(tile_n + row) * Kd + k0 + c8, &sB[(it * 4 + wave) * 512]);
    }
    __syncthreads();

    f16x8 af[4], bfr[4];
    for (int i = 0; i < 4; i++) af[i]  = *(const f16x8*)&sA[(wm + i * 16 + l16) * 32 + quad * 8];
    for (int j = 0; j < 4; j++) bfr[j] = *(const f16x8*)&sB[(wn + j * 16 + l16) * 32 + quad * 8];
    for (int i = 0; i < 4; i++)
      for (int j = 0; j < 4; j++)
        acc[i][j] = __builtin_amdgcn_mfma_f32_16x16x32_f16(af[i], bfr[j], acc[i][j], 0, 0, 0);
  }

  // epilogue: C layout col=lane&15, row=quad*4+reg
  for (int j = 0; j < 4; j++) {
    const int col = tile_n + wn + j * 16 + l16;
    const float bv = bias[col];
    int h = 0, d = 0, s = 0;
    if (MODE == 1) {
      h = col / 288;
      int rem = col - h * 288;
      d = rem / 3;
      s = rem - d * 3;
    }
    for (int i = 0; i < 4; i++) {
      for (int r = 0; r < 4; r++) {
        const int row = tile_m + wm + i * 16 + quad * 4 + r;
        const float fv = acc[i][j][r] + bv;
        if (MODE == 0) {
          Cout[(size_t)row * N + col] = fv;
        } else {
          const f16 o = (f16)fv;
          const int b = bofs + (row >> 11), n = row & 2047;
          const size_t bh = (size_t)(b * NHEADS + h);
          if (s == 0)      Q [(bh * SEQ + n) * HDIM + d] = o;
          else if (s == 1) K [(bh * SEQ + n) * HDIM + d] = o;
          else             Vt[(bh * HDIM + d) * SEQ + n] = o;
        }
      }
    }
  }
}

// ---------------- flash attention ----------------
// grid: (SEQ/128, nb*NHEADS); 256 threads = 4 waves; wave w owns q rows [w*32, w*32+32)
// K-tile staged in LDS (padded, conflict-free); V direct from global; sP padded.
__global__ __launch_bounds__(256) void attn_k(
    const f16* __restrict__ Q, const f16* __restrict__ K,
    const f16* __restrict__ Vt, f16* __restrict__ Out /* [nb,N,EMB] f16 */)
{
  __shared__ f16 sK[128][104];  // 26624 B; stride 104 f16 -> 2-way (free) b128 reads
  __shared__ f16 sP[128][136];  // 34816 B; stride 136 f16 -> 2-way reads/stores
  const int tid  = threadIdx.x;
  const int wave = tid >> 6, lane = tid & 63;
  const int quad = lane >> 4, l16 = lane & 15;
  const int qt = blockIdx.x;
  const int bh = blockIdx.y;           // launch-local
  const int b = bh >> 3, h = bh & 7;

  const f16* Qb = Q  + ((size_t)bh * SEQ + qt * 128) * HDIM;
  const f16* Kb = K  + (size_t)bh * SEQ * HDIM;
  const f16* Vb = Vt + (size_t)bh * HDIM * SEQ;

  // Q fragments: A[m=l16][k=quad*8+j]
  f16x8 qf[2][3];
  for (int ti = 0; ti < 2; ti++)
    for (int kc = 0; kc < 3; kc++)
      qf[ti][kc] = *(const f16x8*)(Qb + (size_t)(wave * 32 + ti * 16 + l16) * HDIM + kc * 32 + quad * 8);

  f32x4 oacc[2][6];
  for (int ti = 0; ti < 2; ti++)
    for (int dj = 0; dj < 6; dj++)
      oacc[ti][dj] = f32x4{0.f, 0.f, 0.f, 0.f};
  f32x4 m_run[2], l_run[2];
  for (int ti = 0; ti < 2; ti++) {
    m_run[ti] = f32x4{-1e30f, -1e30f, -1e30f, -1e30f};
    l_run[ti] = f32x4{0.f, 0.f, 0.f, 0.f};
  }

  for (int kt = 0; kt < SEQ / 128; kt++) {
    // ---- stage K tile (contiguous 24KB in global) into padded LDS ----
    __syncthreads();
    {
      const f16* kt_base = Kb + (size_t)kt * 128 * HDIM;
#pragma unroll
      for (int i = 0; i < 6; i++) {
        const int c = i * 256 + tid;            // 0..1535 chunks of 8 f16
        const int row = c / 12, col = (c % 12) * 8;
        *(uint4*)&sK[row][col] = *(const uint4*)(kt_base + (size_t)c * 8);
      }
    }
    __syncthreads();

    // ---- S = Q * Ktile^T ----
    f32x4 sacc[2][8];
    for (int ti = 0; ti < 2; ti++)
      for (int j = 0; j < 8; j++)
        sacc[ti][j] = f32x4{0.f, 0.f, 0.f, 0.f};
    for (int kc = 0; kc < 3; kc++) {
      for (int j = 0; j < 8; j++) {
        f16x8 kf = *(const f16x8*)&sK[j * 16 + l16][kc * 32 + quad * 8];
        sacc[0][j] = __builtin_amdgcn_mfma_f32_16x16x32_f16(qf[0][kc], kf, sacc[0][j], 0, 0, 0);
        sacc[1][j] = __builtin_amdgcn_mfma_f32_16x16x32_f16(qf[1][kc], kf, sacc[1][j], 0, 0, 0);
      }
    }

    // ---- online softmax, vectorized over the 4 rows (components) ----
    for (int ti = 0; ti < 2; ti++) {
      f32x4 vmx = sacc[ti][0];
      for (int j = 1; j < 8; j++) vmx = vmax4(vmx, sacc[ti][j]);
      for (int m = 1; m < 16; m <<= 1) vmx = vmax4(vmx, shflx4(vmx, m));
      const f32x4 nm = vmax4(m_run[ti], vmx);
      f32x4 alpha;
      alpha[0] = __expf(m_run[ti][0] - nm[0]); alpha[1] = __expf(m_run[ti][1] - nm[1]);
      alpha[2] = __expf(m_run[ti][2] - nm[2]); alpha[3] = __expf(m_run[ti][3] - nm[3]);
      m_run[ti] = nm;
      f32x4 rsv = f32x4{0.f, 0.f, 0.f, 0.f};
      const int prow = wave * 32 + ti * 16 + quad * 4;
      for (int j = 0; j < 8; j++) {
        f32x4 p;
        p[0] = __expf(sacc[ti][j][0] - nm[0]); p[1] = __expf(sacc[ti][j][1] - nm[1]);
        p[2] = __expf(sacc[ti][j][2] - nm[2]); p[3] = __expf(sacc[ti][j][3] - nm[3]);
        rsv += p;
        sP[prow + 0][j * 16 + l16] = (f16)p[0];
        sP[prow + 1][j * 16 + l16] = (f16)p[1];
        sP[prow + 2][j * 16 + l16] = (f16)p[2];
        sP[prow + 3][j * 16 + l16] = (f16)p[3];
      }
      for (int m = 1; m < 16; m <<= 1) rsv += shflx4(rsv, m);
      l_run[ti] = l_run[ti] * alpha + rsv;
      for (int dj = 0; dj < 6; dj++) oacc[ti][dj] *= alpha;
    }

    // ---- O += P @ Vtile ---- (P from own wave's LDS slice; V direct global)
    for (int kc2 = 0; kc2 < 4; kc2++) {
      f16x8 pf0 = *(const f16x8*)&sP[wave * 32 + 0 * 16 + l16][kc2 * 32 + quad * 8];
      f16x8 pf1 = *(const f16x8*)&sP[wave * 32 + 1 * 16 + l16][kc2 * 32 + quad * 8];
      for (int dj = 0; dj < 6; dj++) {
        f16x8 vf = *(const f16x8*)(Vb + (size_t)(dj * 16 + l16) * SEQ + kt * 128 + kc2 * 32 + quad * 8);
        oacc[0][dj] = __builtin_amdgcn_mfma_f32_16x16x32_f16(pf0, vf, oacc[0][dj], 0, 0, 0);
        oacc[1][dj] = __builtin_amdgcn_mfma_f32_16x16x32_f16(pf1, vf, oacc[1][dj], 0, 0, 0);
      }
    }
  }

  const float inv_scale = 0.10206207261596577f;  // 1/sqrt(96), applied AFTER softmax per ref
  for (int ti = 0; ti < 2; ti++) {
    for (int r = 0; r < 4; r++) {
      const int qrow = qt * 128 + wave * 32 + ti * 16 + quad * 4 + r;
      const float invl = inv_scale / l_run[ti][r];
      const size_t base = ((size_t)b * SEQ + qrow) * EMB + h * HDIM;
      for (int dj = 0; dj < 6; dj++) {
        Out[base + dj * 16 + l16] = (f16)(oacc[ti][dj][r] * invl);
      }
    }
  }
}

// ---------------- launch ----------------
extern "C" void kernel_launch(void* const* d_in, const int* in_sizes, int n_in,
                              void* d_out, int out_size, void* d_ws, size_t ws_size,
                              hipStream_t stream) {
  const float* x      = (const float*)d_in[0];
  const float* w_qkv  = (const float*)d_in[1];
  const float* b_qkv  = (const float*)d_in[2];
  const float* w_proj = (const float*)d_in[3];
  const float* b_proj = (const float*)d_in[4];
  float* outF = (float*)d_out;   // fp32 output

  const size_t fixed = 256 + (size_t)QKV_COLS * EMB * 2 + (size_t)EMB * EMB * 2
                     + QKV_COLS * 4 + EMB * 4 + 256;
  const size_t perb = (size_t)4 * PB * 2;  // Q,K,Vt,attn per batch
  int nb = (ws_size >= fixed + 4 * perb) ? 4 : (ws_size >= fixed + 2 * perb) ? 2 : 1;

  char* ws = (char*)d_ws;
  ws += 256;
  f16*   wqkvT  = (f16*)ws;   ws += (size_t)QKV_COLS * EMB * 2;
  f16*   wprojT = (f16*)ws;   ws += (size_t)EMB * EMB * 2;
  float* bq     = (float*)ws; ws += (size_t)QKV_COLS * 4;
  float* bp     = (float*)ws; ws += (size_t)EMB * 4 + 256;
  f16* Q    = (f16*)ws;       ws += (size_t)nb * PB * 2;
  f16* K    = (f16*)ws;       ws += (size_t)nb * PB * 2;
  f16* Vt   = (f16*)ws;       ws += (size_t)nb * PB * 2;
  f16* attn = (f16*)ws;       ws += (size_t)nb * PB * 2;

  conv_transpose_k<<<(EMB * QKV_COLS + 255) / 256, 256, 0, stream>>>(w_qkv, wqkvT, EMB, QKV_COLS);
  conv_transpose_k<<<(EMB * EMB + 255) / 256, 256, 0, stream>>>(w_proj, wprojT, EMB, EMB);
  copy_f32_k<<<(QKV_COLS + 255) / 256, 256, 0, stream>>>(b_qkv, bq, QKV_COLS);
  copy_f32_k<<<(EMB + 255) / 256, 256, 0, stream>>>(b_proj, bp, EMB);

  const int qb = (nb >= 2) ? 2 : 1;          // batches per qkv GEMM
  for (int outer = 0; outer < BATCH / nb; outer++) {
    const int bbase = outer * nb;

    for (int gg = 0; gg < nb / qb; gg++) {
      const int b0 = bbase + gg * qb;
      const size_t goff = (size_t)b0 * PB;
      f16* xg = (f16*)(outF + goff);         // stage f16 x inside fp32 out region (dead before proj)
      const int n8 = (int)((size_t)qb * PB / 8);
      conv_x8_k<<<(n8 + 255) / 256, 256, 0, stream>>>(x, goff, xg, n8);

      dim3 g1(QKV_COLS / 128, qb * SEQ / 128);
      gemm_bt<1><<<g1, 256, 0, stream>>>(xg, wqkvT, bq, nullptr, Q, K, Vt,
                                         qb * SEQ, QKV_COLS, EMB, gg * qb);
    }

    dim3 g2(SEQ / 128, nb * NHEADS);
    attn_k<<<g2, 256, 0, stream>>>(Q, K, Vt, attn);

    dim3 g3(EMB / 128, nb * SEQ / 128);
    gemm_bt<0><<<g3, 256, 0, stream>>>(attn, wprojT, bp, outF + (size_t)bbase * PB,
                                       nullptr, nullptr, nullptr,
                                       nb * SEQ, EMB, EMB, 0);
  }
}

// Round 8
// 390.298 us; speedup vs baseline: 2.4209x; 1.8868x over previous
//
#include <hip/hip_runtime.h>
#include <hip/hip_bf16.h>

#define EMB 768
#define NHEADS 8
#define HDIM 96
#define SEQ 2048
#define BATCH 4
#define QKV_COLS 2304
#define PB ((size_t)SEQ * EMB)   // per-batch elements

typedef _Float16 f16;
typedef _Float16 f16x8 __attribute__((ext_vector_type(8)));
typedef float f32x4 __attribute__((ext_vector_type(4)));

__device__ __forceinline__ void gl_lds16(const f16* g, f16* l) {
  __builtin_amdgcn_global_load_lds((const __attribute__((address_space(1))) void*)g,
                                   (__attribute__((address_space(3))) void*)l, 16, 0, 0);
}
__device__ __forceinline__ f32x4 shflx4(f32x4 v, int m) {
  f32x4 r;
  r[0] = __shfl_xor(v[0], m); r[1] = __shfl_xor(v[1], m);
  r[2] = __shfl_xor(v[2], m); r[3] = __shfl_xor(v[3], m);
  return r;
}
__device__ __forceinline__ f32x4 vmax4(f32x4 a, f32x4 b) {
  f32x4 r;
  r[0] = fmaxf(a[0], b[0]); r[1] = fmaxf(a[1], b[1]);
  r[2] = fmaxf(a[2], b[2]); r[3] = fmaxf(a[3], b[3]);
  return r;
}

// ---------------- conversions ----------------
__global__ __launch_bounds__(256) void conv_x8_k(const float* __restrict__ in, size_t in_off,
                                                 f16* __restrict__ out, int n8) {
  int i = blockIdx.x * 256 + threadIdx.x;
  if (i >= n8) return;
  const float4 a = *(const float4*)(in + in_off + (size_t)i * 8);
  const float4 b = *(const float4*)(in + in_off + (size_t)i * 8 + 4);
  f16x8 o;
  o[0] = (f16)a.x; o[1] = (f16)a.y; o[2] = (f16)a.z; o[3] = (f16)a.w;
  o[4] = (f16)b.x; o[5] = (f16)b.y; o[6] = (f16)b.z; o[7] = (f16)b.w;
  *(f16x8*)(out + (size_t)i * 8) = o;
}

// qkv weight: transpose + column-permute. out[col'][r], col' = s*768+h*96+d,
// original col c = h*288+d*3+s. Output-indexed -> coalesced 16B writes.
__global__ __launch_bounds__(256) void wqkv_perm_k(const float* __restrict__ in,
                                                   f16* __restrict__ out) {
  int t = blockIdx.x * 256 + threadIdx.x;          // 0 .. 2304*96-1
  if (t >= QKV_COLS * (EMB / 8)) return;
  const int colp = t / (EMB / 8);
  const int r8 = (t - colp * (EMB / 8)) * 8;
  const int s = colp / 768, rem = colp - s * 768;
  const int h = rem / 96, d = rem - h * 96;
  const int c = h * 288 + d * 3 + s;
  f16x8 o;
#pragma unroll
  for (int i = 0; i < 8; i++) o[i] = (f16)in[(size_t)(r8 + i) * QKV_COLS + c];
  *(f16x8*)(out + (size_t)colp * EMB + r8) = o;
}

// proj weight: plain transpose, output-indexed.
__global__ __launch_bounds__(256) void wproj_t_k(const float* __restrict__ in,
                                                 f16* __restrict__ out) {
  int t = blockIdx.x * 256 + threadIdx.x;          // 0 .. 768*96-1
  if (t >= EMB * (EMB / 8)) return;
  const int cp = t / (EMB / 8);
  const int r8 = (t - cp * (EMB / 8)) * 8;
  f16x8 o;
#pragma unroll
  for (int i = 0; i < 8; i++) o[i] = (f16)in[(size_t)(r8 + i) * EMB + cp];
  *(f16x8*)(out + (size_t)cp * EMB + r8) = o;
}

// bias: permute qkv bias to col' space; copy proj bias.
__global__ __launch_bounds__(256) void bias_perm_k(const float* __restrict__ bq_in,
                                                   float* __restrict__ bq_out,
                                                   const float* __restrict__ bp_in,
                                                   float* __restrict__ bp_out) {
  int i = blockIdx.x * 256 + threadIdx.x;
  if (i < QKV_COLS) {
    const int s = i / 768, rem = i - s * 768;
    const int h = rem / 96, d = rem - h * 96;
    bq_out[i] = bq_in[h * 288 + d * 3 + s];
  }
  if (i < EMB) bp_out[i] = bp_in[i];
}

// ---------------- bt-GEMM: C[M,N] = A[M,K] @ Bt[N,K]^T + bias ----------------
// MODE 0: fp32 store to Cout [M,N]
// MODE 1 (permuted qkv): tile_n < 1536 -> QK[row][1536] direct (coalesced);
//                        tile_n >= 1536 -> V: LDS transpose -> Vt[bh][d][n] coalesced
template<int MODE>
__global__ __launch_bounds__(256) void gemm_bt(
    const f16* __restrict__ A, const f16* __restrict__ Bt,
    const float* __restrict__ bias, float* __restrict__ Cout,
    f16* __restrict__ QK, f16* __restrict__ Vt,
    int M, int N, int Kd)
{
  __shared__ f16 smem[MODE == 1 ? 17408 : 8192];   // sA[4096]+sB[4096]; V-epilogue reuses as sT[128][136]
  f16* sA = smem;
  f16* sB = smem + 4096;
  const int tid  = threadIdx.x;
  const int wave = tid >> 6, lane = tid & 63;
  const int quad = lane >> 4, l16 = lane & 15;
  const int tile_m = blockIdx.y * 128, tile_n = blockIdx.x * 128;
  const int wm = (wave >> 1) * 64, wn = (wave & 1) * 64;

  f32x4 acc[4][4];
  for (int i = 0; i < 4; i++)
    for (int j = 0; j < 4; j++)
      acc[i][j] = f32x4{0.f, 0.f, 0.f, 0.f};

  for (int k0 = 0; k0 < Kd; k0 += 32) {
    __syncthreads();
#pragma unroll
    for (int it = 0; it < 2; it++) {
      const int ch  = (it * 4 + wave) * 64 + lane;   // 0..511
      const int row = ch >> 2, c8 = (ch & 3) * 8;
      gl_lds16(A  + (size_t)(tile_m + row) * Kd + k0 + c8, &sA[(it * 4 + wave) * 512]);
      gl_lds16(Bt + (size_t)(tile_n + row) * Kd + k0 + c8, &sB[(it * 4 + wave) * 512]);
    }
    __syncthreads();

    f16x8 af[4], bfr[4];
    for (int i = 0; i < 4; i++) af[i]  = *(const f16x8*)&sA[(wm + i * 16 + l16) * 32 + quad * 8];
    for (int j = 0; j < 4; j++) bfr[j] = *(const f16x8*)&sB[(wn + j * 16 + l16) * 32 + quad * 8];
    for (int i = 0; i < 4; i++)
      for (int j = 0; j < 4; j++)
        acc[i][j] = __builtin_amdgcn_mfma_f32_16x16x32_f16(af[i], bfr[j], acc[i][j], 0, 0, 0);
  }

  // epilogue: C layout col=lane&15, row=quad*4+reg
  if (MODE == 1 && tile_n >= 1536) {
    // ---- V tile: LDS transpose then coalesced Vt writes ----
    __syncthreads();   // sA/sB dead, safe to overwrite
    f16* sT = smem;    // [128][136]
    for (int j = 0; j < 4; j++) {
      const int cl = wn + j * 16 + l16;
      const float bv = bias[tile_n + cl];
      for (int i = 0; i < 4; i++)
        for (int r = 0; r < 4; r++)
          sT[cl * 136 + wm + i * 16 + quad * 4 + r] = (f16)(acc[i][j][r] + bv);
    }
    __syncthreads();
    const int bb = tile_m >> 11;          // group-local batch
    const int n0 = tile_m & 2047;
#pragma unroll
    for (int l = 0; l < 8; l++) {
      const int cc = l * 256 + tid;       // 0..2047 chunks of 8 f16
      const int rh = cc >> 4, nof = (cc & 15) * 8;
      const int hd = (tile_n - 1536) + rh;
      const int h = hd / 96, d = hd - h * 96;
      f16x8 v = *(const f16x8*)&sT[rh * 136 + nof];
      *(f16x8*)(Vt + ((size_t)(bb * NHEADS + h) * HDIM + d) * SEQ + n0 + nof) = v;
    }
  } else {
    for (int j = 0; j < 4; j++) {
      const int col = tile_n + wn + j * 16 + l16;
      const float bv = bias[col];
      for (int i = 0; i < 4; i++) {
        for (int r = 0; r < 4; r++) {
          const int row = tile_m + wm + i * 16 + quad * 4 + r;
          const float fv = acc[i][j][r] + bv;
          if (MODE == 0) Cout[(size_t)row * N + col] = fv;
          else           QK  [(size_t)row * 1536 + col] = (f16)fv;  // Q cols 0..767, K 768..1535
        }
      }
    }
  }
}

// ---------------- flash attention ----------------
// grid: (SEQ/128, nb*NHEADS); 4 waves; wave w owns q rows [w*32, w*32+32)
// Q/K read from QK[row][1536] (Q at h*96, K at 768+h*96); V from Vt[bh][d][n].
__global__ __launch_bounds__(256) void attn_k(
    const f16* __restrict__ QK, const f16* __restrict__ Vt,
    f16* __restrict__ Out /* [nb,N,EMB] f16 */)
{
  __shared__ f16 sK[128][104];
  __shared__ f16 sP[128][136];
  const int tid  = threadIdx.x;
  const int wave = tid >> 6, lane = tid & 63;
  const int quad = lane >> 4, l16 = lane & 15;
  const int qt = blockIdx.x;
  const int bh = blockIdx.y;           // launch-local
  const int b = bh >> 3, h = bh & 7;

  const f16* Qb = QK + (size_t)(b * SEQ + qt * 128) * 1536 + h * 96;
  const f16* Kb = QK + (size_t)(b * SEQ) * 1536 + 768 + h * 96;
  const f16* Vb = Vt + (size_t)bh * HDIM * SEQ;

  f16x8 qf[2][3];
  for (int ti = 0; ti < 2; ti++)
    for (int kc = 0; kc < 3; kc++)
      qf[ti][kc] = *(const f16x8*)(Qb + (size_t)(wave * 32 + ti * 16 + l16) * 1536 + kc * 32 + quad * 8);

  f32x4 oacc[2][6];
  for (int ti = 0; ti < 2; ti++)
    for (int dj = 0; dj < 6; dj++)
      oacc[ti][dj] = f32x4{0.f, 0.f, 0.f, 0.f};
  f32x4 m_run[2], l_run[2];
  for (int ti = 0; ti < 2; ti++) {
    m_run[ti] = f32x4{-1e30f, -1e30f, -1e30f, -1e30f};
    l_run[ti] = f32x4{0.f, 0.f, 0.f, 0.f};
  }

  for (int kt = 0; kt < SEQ / 128; kt++) {
    __syncthreads();
    {
      const f16* kt_base = Kb + (size_t)(kt * 128) * 1536;
#pragma unroll
      for (int i = 0; i < 6; i++) {
        const int c = i * 256 + tid;            // 1536 chunks of 8 f16
        const int row = c / 12, col = (c % 12) * 8;
        *(uint4*)&sK[row][col] = *(const uint4*)(kt_base + (size_t)row * 1536 + col);
      }
    }
    __syncthreads();

    f32x4 sacc[2][8];
    for (int ti = 0; ti < 2; ti++)
      for (int j = 0; j < 8; j++)
        sacc[ti][j] = f32x4{0.f, 0.f, 0.f, 0.f};
    for (int kc = 0; kc < 3; kc++) {
      for (int j = 0; j < 8; j++) {
        f16x8 kf = *(const f16x8*)&sK[j * 16 + l16][kc * 32 + quad * 8];
        sacc[0][j] = __builtin_amdgcn_mfma_f32_16x16x32_f16(qf[0][kc], kf, sacc[0][j], 0, 0, 0);
        sacc[1][j] = __builtin_amdgcn_mfma_f32_16x16x32_f16(qf[1][kc], kf, sacc[1][j], 0, 0, 0);
      }
    }

    for (int ti = 0; ti < 2; ti++) {
      f32x4 vmx = sacc[ti][0];
      for (int j = 1; j < 8; j++) vmx = vmax4(vmx, sacc[ti][j]);
      for (int m = 1; m < 16; m <<= 1) vmx = vmax4(vmx, shflx4(vmx, m));
      const f32x4 nm = vmax4(m_run[ti], vmx);
      f32x4 alpha;
      alpha[0] = __expf(m_run[ti][0] - nm[0]); alpha[1] = __expf(m_run[ti][1] - nm[1]);
      alpha[2] = __expf(m_run[ti][2] - nm[2]); alpha[3] = __expf(m_run[ti][3] - nm[3]);
      m_run[ti] = nm;
      f32x4 rsv = f32x4{0.f, 0.f, 0.f, 0.f};
      const int prow = wave * 32 + ti * 16 + quad * 4;
      for (int j = 0; j < 8; j++) {
        f32x4 p;
        p[0] = __expf(sacc[ti][j][0] - nm[0]); p[1] = __expf(sacc[ti][j][1] - nm[1]);
        p[2] = __expf(sacc[ti][j][2] - nm[2]); p[3] = __expf(sacc[ti][j][3] - nm[3]);
        rsv += p;
        sP[prow + 0][j * 16 + l16] = (f16)p[0];
        sP[prow + 1][j * 16 + l16] = (f16)p[1];
        sP[prow + 2][j * 16 + l16] = (f16)p[2];
        sP[prow + 3][j * 16 + l16] = (f16)p[3];
      }
      for (int m = 1; m < 16; m <<= 1) rsv += shflx4(rsv, m);
      l_run[ti] = l_run[ti] * alpha + rsv;
      for (int dj = 0; dj < 6; dj++) oacc[ti][dj] *= alpha;
    }

    for (int kc2 = 0; kc2 < 4; kc2++) {
      f16x8 pf0 = *(const f16x8*)&sP[wave * 32 + 0 * 16 + l16][kc2 * 32 + quad * 8];
      f16x8 pf1 = *(const f16x8*)&sP[wave * 32 + 1 * 16 + l16][kc2 * 32 + quad * 8];
      for (int dj = 0; dj < 6; dj++) {
        f16x8 vf = *(const f16x8*)(Vb + (size_t)(dj * 16 + l16) * SEQ + kt * 128 + kc2 * 32 + quad * 8);
        oacc[0][dj] = __builtin_amdgcn_mfma_f32_16x16x32_f16(pf0, vf, oacc[0][dj], 0, 0, 0);
        oacc[1][dj] = __builtin_amdgcn_mfma_f32_16x16x32_f16(pf1, vf, oacc[1][dj], 0, 0, 0);
      }
    }
  }

  const float inv_scale = 0.10206207261596577f;  // 1/sqrt(96), applied AFTER softmax per ref
  for (int ti = 0; ti < 2; ti++) {
    for (int r = 0; r < 4; r++) {
      const int qrow = qt * 128 + wave * 32 + ti * 16 + quad * 4 + r;
      const float invl = inv_scale / l_run[ti][r];
      const size_t base = ((size_t)b * SEQ + qrow) * EMB + h * HDIM;
      for (int dj = 0; dj < 6; dj++) {
        Out[base + dj * 16 + l16] = (f16)(oacc[ti][dj][r] * invl);
      }
    }
  }
}

// ---------------- launch ----------------
extern "C" void kernel_launch(void* const* d_in, const int* in_sizes, int n_in,
                              void* d_out, int out_size, void* d_ws, size_t ws_size,
                              hipStream_t stream) {
  const float* x      = (const float*)d_in[0];
  const float* w_qkv  = (const float*)d_in[1];
  const float* b_qkv  = (const float*)d_in[2];
  const float* w_proj = (const float*)d_in[3];
  const float* b_proj = (const float*)d_in[4];
  float* outF = (float*)d_out;   // fp32 output

  const size_t fixed = 256 + (size_t)QKV_COLS * EMB * 2 + (size_t)EMB * EMB * 2
                     + QKV_COLS * 4 + EMB * 4 + 256;
  const size_t perb = (size_t)4 * PB * 2;  // QK(2) + Vt(1) + attn(1) per batch, in PB units
  int nb = (ws_size >= fixed + 4 * perb) ? 4 : (ws_size >= fixed + 2 * perb) ? 2 : 1;

  char* ws = (char*)d_ws;
  ws += 256;
  f16*   wqkvT  = (f16*)ws;   ws += (size_t)QKV_COLS * EMB * 2;
  f16*   wprojT = (f16*)ws;   ws += (size_t)EMB * EMB * 2;
  float* bq     = (float*)ws; ws += (size_t)QKV_COLS * 4;
  float* bp     = (float*)ws; ws += (size_t)EMB * 4 + 256;
  f16* QK   = (f16*)ws;       ws += (size_t)nb * 2 * PB * 2;   // [nb*2048][1536]
  f16* Vt   = (f16*)ws;       ws += (size_t)nb * PB * 2;       // [nb*8][96][2048]
  f16* attn = (f16*)ws;       ws += (size_t)nb * PB * 2;       // [nb][2048][768]

  wqkv_perm_k<<<(QKV_COLS * (EMB / 8) + 255) / 256, 256, 0, stream>>>(w_qkv, wqkvT);
  wproj_t_k<<<(EMB * (EMB / 8) + 255) / 256, 256, 0, stream>>>(w_proj, wprojT);
  bias_perm_k<<<(QKV_COLS + 255) / 256, 256, 0, stream>>>(b_qkv, bq, b_proj, bp);

  for (int outer = 0; outer < BATCH / nb; outer++) {
    const int bbase = outer * nb;
    const size_t goff = (size_t)bbase * PB;
    f16* xg = (f16*)(outF + goff);           // stage f16 x inside fp32 out region (dead before proj)
    const int n8 = (int)((size_t)nb * PB / 8);
    conv_x8_k<<<(n8 + 255) / 256, 256, 0, stream>>>(x, goff, xg, n8);

    dim3 g1(QKV_COLS / 128, nb * SEQ / 128);
    gemm_bt<1><<<g1, 256, 0, stream>>>(xg, wqkvT, bq, nullptr, QK, Vt,
                                       nb * SEQ, QKV_COLS, EMB);

    dim3 g2(SEQ / 128, nb * NHEADS);
    attn_k<<<g2, 256, 0, stream>>>(QK, Vt, attn);

    dim3 g3(EMB / 128, nb * SEQ / 128);
    gemm_bt<0><<<g3, 256, 0, stream>>>(attn, wprojT, bp, outF + goff,
                                       nullptr, nullptr,
                                       nb * SEQ, EMB, EMB);
  }
}